// Round 11
// baseline (304.565 us; speedup 1.0000x reference)
//
#include <hip/hip_runtime.h>
#include <hip/hip_bf16.h>

typedef __attribute__((ext_vector_type(8))) short bf16x8;
typedef __attribute__((ext_vector_type(4))) float f32x4;
typedef __attribute__((ext_vector_type(8))) float f32x8;
typedef __attribute__((ext_vector_type(2))) float f32x2;
typedef __attribute__((ext_vector_type(8))) __bf16 bfv8;
typedef __attribute__((ext_vector_type(4))) __bf16 bfv4;
typedef __attribute__((ext_vector_type(2))) __bf16 bfv2;
typedef __attribute__((ext_vector_type(2))) unsigned int u32x2;

#define B_ 2
#define S_ 2048
#define H_ 32
#define KVH_ 8
#define D_ 128
#define BM 128
#define BN 64
#define NQT (S_ / BM)   // 16
#define NQP (NQT / 2)   // 8 q-tile pairs
#define FRAG 512        // shorts per fragment (64 lanes x 8 bf16)
#define TILEF (16 * FRAG) // shorts per fragment-major tile (16 frags)

__device__ __forceinline__ bf16x8 cvt8(f32x8 v) {
    union { bfv8 b; bf16x8 s; } u;
    u.b = __builtin_convertvector(v, bfv8);
    return u.s;
}

// ---- merged pre-pass: K and V fp32 -> bf16 FRAGMENT-MAJOR tiles ----
// Fragment-major layout: per (z, ti) tile, fragment fi, lane ln: the 16B
// slice held by lane ln for MFMA fragment fi is at
//   base + ((z*32+ti)*16 + fi)*512 + ln*8   (shorts)
// so the fa kernel's kf/vf loads are perfectly coalesced 1KB wave-loads.
// K: fi = c*4+nb; lane(quad,l16) holds K[z][ti*64+nb*16+l16][c*32+quad*8+j].
// V: fi = kk*8+db; lane(qv,l16) holds Vsig[z][db*16+l16][ti*64+(kk*4+qv)*8+j]
//    (Vsig = sigma-permuted transpose; same logical data as verified in r9).
__global__ __launch_bounds__(256) void conv_kv(const float* __restrict__ k,
                                               const float* __restrict__ v,
                                               short* __restrict__ kfr,
                                               short* __restrict__ vfr) {
    __shared__ short tl[64 * 136];   // K path: 272B rows (16B-aligned)
    const int tid = threadIdx.x;
    if (blockIdx.x < 512) {
        // ---- K -> fragment-major ----
        const int z  = blockIdx.x >> 5;
        const int ti = blockIdx.x & 31;
        const float* kz = k + ((size_t)z * S_ + ti * 64) * D_;
        #pragma unroll
        for (int i = 0; i < 4; ++i) {
            const int chunk = i * 256 + tid;     // 1024 runs of 8
            const int t = chunk >> 4;
            const int g = chunk & 15;
            f32x8 a = *(const f32x8*)(kz + (size_t)t * D_ + g * 8);
            *(bf16x8*)(&tl[t * 136 + g * 8]) = cvt8(a);
        }
        __syncthreads();
        short* dst = kfr + (size_t)(z * 32 + ti) * TILEF;
        #pragma unroll
        for (int i = 0; i < 4; ++i) {
            const int chunk = i * 256 + tid;
            const int fi = chunk >> 6;           // c*4+nb
            const int ln = chunk & 63;           // quad*16+l16
            const int c  = fi >> 2, nb = fi & 3;
            const int qd = ln >> 4, l16 = ln & 15;
            bf16x8 r = *(const bf16x8*)(&tl[(nb * 16 + l16) * 136 + c * 32 + qd * 8]);
            *(bf16x8*)(dst + ((size_t)fi * 64 + ln) * 8) = r;
        }
    } else {
        // ---- V -> sigma-transpose, fragment-major ----
        const int f  = blockIdx.x - 512;
        const int d0 = (f & 1) * 64;
        const int ti = (f >> 1) & 31;
        const int z  = f >> 6;
        const float* vb = v + ((size_t)z * S_ + ti * 64) * D_;
        #pragma unroll
        for (int i = 0; i < 4; ++i) {
            const int chunk = i * 256 + tid;
            const int tr = chunk >> 4;
            const int c4 = (chunk & 15) << 2;
            float4 fv = *(const float4*)(vb + (size_t)tr * D_ + d0 + c4);
            union { bfv4 b; ushort4 s; } u;
            u.b = __builtin_convertvector((f32x4){fv.x, fv.y, fv.z, fv.w}, bfv4);
            *(ushort4*)(&tl[tr * 68 + c4]) = u.s;
        }
        __syncthreads();
        short* dst = vfr + (size_t)(z * 32 + ti) * TILEF;
        #pragma unroll
        for (int i = 0; i < 2; ++i) {
            const int chunk = i * 256 + tid;     // 512 cells: 8 fi x 64 lanes
            const int fx = chunk >> 6;           // kk*4 + db_loc
            const int ln = chunk & 63;           // qv*16 + l16v
            const int kk = fx >> 2, dbl = fx & 3;
            const int qv = ln >> 4, l16v = ln & 15;
            const int dl = dbl * 16 + l16v;      // local d 0..63
            const int sg = kk * 4 + qv;          // slot group 0..7
            bf16x8 r;
            #pragma unroll
            for (int w = 0; w < 8; ++w) {
                const int t = 2 * sg + (w >> 2) + 16 * (w & 3);  // sigma^-1(8sg+w)
                r[w] = tl[t * 68 + dl];
            }
            const int fi = kk * 8 + (d0 >> 4) + dbl;
            *(bf16x8*)(dst + ((size_t)fi * 64 + ln) * 8) = r;
        }
    }
}

// ---- main flash-attention kernel: ZERO-barrier, LDS = P-scratch only ----
// r2..r10: every K/V-through-LDS structure pins at 118-132us (LDS pipe
// ~192KB/block-tile + 36 full-drain barrier points = the floor). This
// version reads K/V fragments DIRECTLY from L2 via coalesced 1KB wave
// loads (fragment-major layout above): no lds_k/lds_v, no STAGE, no
// s_barrier, no vmcnt asm. Waves are fully independent; each wave loops
// only over its own ntw causal tiles.
// KEY INVARIANTS: causal pairing {qp, 15-qp} (uniform work, r6); vf shared
// across both mb blocks (r5); launch_bounds min-occupancy 2 (r4: higher
// forces 64-VGPR spill; r8: lower lets allocator pick 128 and spill).
// Watch: VGPR ~170-210 OK, WRITE_SIZE must stay 65.5MB (no spill).
__global__ __launch_bounds__(256, 2) void fa_fwd(
    const float* __restrict__ q, const short* __restrict__ kfr,
    const short* __restrict__ vfr, float* __restrict__ out)
{
    __shared__ short lds_p[4 * 16 * 64];  // 8 KB (per-wave 16x64 P, two passes)

    // ---- XCD-aware block swizzle (T1): each XCD owns 2 (b,kvh) groups ----
    const int flat = blockIdx.x + NQP * (blockIdx.y + H_ * blockIdx.z);
    const int xcd  = flat & 7;
    const int idx  = flat >> 3;              // 0..63 dispatch order within XCD
    const int work = xcd * 64 + idx;         // contiguous work chunk per XCD
    const int bkvh = work >> 5;              // 0..15 = b*KVH + kvh
    const int rem  = work & 31;
    const int qp   = rem >> 2;               // 0..7 pair index
    const int b    = bkvh >> 3;
    const int kvh  = bkvh & 7;
    const int h    = (kvh << 2) | (rem & 3); // 4 heads of the group adjacent

    const int tid  = threadIdx.x;
    const int wave = __builtin_amdgcn_readfirstlane(tid >> 6);
    const int lane = tid & 63;
    const int quad = lane >> 4;
    const int l16  = lane & 15;

    const float sl2e = 0.08838834764831843f * 1.4426950408889634f; // scale*log2e

    const short* kt = kfr + (size_t)(b * KVH_ + kvh) * 32 * TILEF;
    const short* vt = vfr + (size_t)(b * KVH_ + kvh) * 32 * TILEF;
    short* pw = lds_p + wave * 1024;   // wave-private 16x64

    #pragma unroll 1
    for (int phase = 0; phase < 2; ++phase) {
        const int qt = phase ? (NQT - 1 - qp) : qp;
        const int wr = qt * BM + wave * 32;    // wave's first query row
        const int ntw = ((wr + 31) >> 6) + 1;  // tiles THIS WAVE needs

        // Q fragments (A-layout), pre-scaled by scale*log2e
        bf16x8 qf[2][4];
        #pragma unroll
        for (int mb = 0; mb < 2; ++mb) {
            const float* qrow = q + (size_t)((b * S_ + wr + mb * 16 + l16) * H_ + h) * D_;
            #pragma unroll
            for (int c = 0; c < 4; ++c) {
                f32x8 a = *(const f32x8*)(qrow + c * 32 + quad * 8);
                qf[mb][c] = cvt8(a * sl2e);
            }
        }

        f32x4 o[2][8];
        #pragma unroll
        for (int mb = 0; mb < 2; ++mb)
            #pragma unroll
            for (int db = 0; db < 8; ++db) o[mb][db] = (f32x4){0.f, 0.f, 0.f, 0.f};
        float Lr[2][4] = {{0.f,0.f,0.f,0.f},{0.f,0.f,0.f,0.f}};

        for (int ti = 0; ti < ntw; ++ti) {
            const short* kfb = kt + (size_t)ti * TILEF;
            const short* vfb = vt + (size_t)ti * TILEF;
            const int t0 = ti * BN;

            // ---- S = Q K^T (kf: coalesced 1KB global loads from L2) ----
            f32x4 sc[2][4];
            #pragma unroll
            for (int mb = 0; mb < 2; ++mb)
                #pragma unroll
                for (int nb = 0; nb < 4; ++nb) sc[mb][nb] = (f32x4){0.f,0.f,0.f,0.f};
            __builtin_amdgcn_s_setprio(1);
            #pragma unroll
            for (int c = 0; c < 4; ++c) {
                #pragma unroll
                for (int nb = 0; nb < 4; ++nb) {
                    bf16x8 kf = *(const bf16x8*)(kfb + ((size_t)(c * 4 + nb) * 64 + lane) * 8);
                    sc[0][nb] = __builtin_amdgcn_mfma_f32_16x16x32_bf16(qf[0][c], kf, sc[0][nb], 0, 0, 0);
                    sc[1][nb] = __builtin_amdgcn_mfma_f32_16x16x32_bf16(qf[1][c], kf, sc[1][nb], 0, 0, 0);
                }
            }
            __builtin_amdgcn_s_setprio(0);

            // ---- softmax, fixed basis ----
            const bool needmask = (t0 + BN - 1 > wr);
            if (needmask) {
                #pragma unroll
                for (int mb = 0; mb < 2; ++mb)
                    #pragma unroll
                    for (int nb = 0; nb < 4; ++nb)
                        #pragma unroll
                        for (int r = 0; r < 4; ++r) {
                            const int tcol = t0 + nb * 16 + l16;
                            const int srow = wr + mb * 16 + quad * 4 + r;
                            if (tcol > srow) sc[mb][nb][r] = -1e30f;
                        }
            }
            #pragma unroll
            for (int mb = 0; mb < 2; ++mb)
                #pragma unroll
                for (int nb = 0; nb < 4; ++nb)
                    #pragma unroll
                    for (int r = 0; r < 4; ++r)
                        sc[mb][nb][r] = exp2f(sc[mb][nb][r]);
            #pragma unroll
            for (int mb = 0; mb < 2; ++mb)
                #pragma unroll
                for (int r = 0; r < 4; ++r)
                    Lr[mb][r] += (sc[mb][0][r] + sc[mb][1][r]) + (sc[mb][2][r] + sc[mb][3][r]);

            // ---- vf kk=0 batch: issue now, lands under P round-trip ----
            bf16x8 vf0[8];
            #pragma unroll
            for (int db = 0; db < 8; ++db)
                vf0[db] = *(const bf16x8*)(vfb + ((size_t)db * 64 + lane) * 8);

            // ---- P -> LDS in two 16-row passes (wave-private), pf -> regs ----
            bf16x8 pf[2][2];
            const int x7 = l16 & 7;
            #pragma unroll
            for (int mb = 0; mb < 2; ++mb) {
                #pragma unroll
                for (int r = 0; r < 4; ++r) {
                    const int rw = quad * 4 + r;
                    union { bfv2 b; unsigned u; } p0, p1;
                    p0.b = __builtin_convertvector((f32x2){sc[mb][0][r], sc[mb][1][r]}, bfv2);
                    p1.b = __builtin_convertvector((f32x2){sc[mb][2][r], sc[mb][3][r]}, bfv2);
                    *(u32x2*)(&pw[rw * 64 + (((l16 >> 1) ^ (rw & 7)) * 8) + (l16 & 1) * 4]) =
                        (u32x2){p0.u, p1.u};
                }
                #pragma unroll
                for (int kk = 0; kk < 2; ++kk)
                    pf[mb][kk] = *(const bf16x8*)(&pw[l16 * 64 +
                                                     (((kk * 4 + quad) ^ x7) * 8)]);
            }

            // ---- vf kk=1 batch ----
            bf16x8 vf1[8];
            #pragma unroll
            for (int db = 0; db < 8; ++db)
                vf1[db] = *(const bf16x8*)(vfb + ((size_t)(8 + db) * 64 + lane) * 8);

            // ---- O += P V: vf shared across both mb blocks ----
            __builtin_amdgcn_s_setprio(1);
            #pragma unroll
            for (int db = 0; db < 8; ++db) {
                o[0][db] = __builtin_amdgcn_mfma_f32_16x16x32_bf16(pf[0][0], vf0[db], o[0][db], 0, 0, 0);
                o[1][db] = __builtin_amdgcn_mfma_f32_16x16x32_bf16(pf[1][0], vf0[db], o[1][db], 0, 0, 0);
            }
            #pragma unroll
            for (int db = 0; db < 8; ++db) {
                o[0][db] = __builtin_amdgcn_mfma_f32_16x16x32_bf16(pf[0][1], vf1[db], o[0][db], 0, 0, 0);
                o[1][db] = __builtin_amdgcn_mfma_f32_16x16x32_bf16(pf[1][1], vf1[db], o[1][db], 0, 0, 0);
            }
            __builtin_amdgcn_s_setprio(0);
        }

        // ---- epilogue for this q-tile: L-reduce, scale, store ----
        #pragma unroll
        for (int mb = 0; mb < 2; ++mb)
            #pragma unroll
            for (int r = 0; r < 4; ++r) {
                float l = Lr[mb][r];
                l += __shfl_xor(l, 1, 16);
                l += __shfl_xor(l, 2, 16);
                l += __shfl_xor(l, 4, 16);
                l += __shfl_xor(l, 8, 16);
                Lr[mb][r] = 1.0f / l;
            }
        #pragma unroll
        for (int mb = 0; mb < 2; ++mb)
            #pragma unroll
            for (int r = 0; r < 4; ++r) {
                const int srow = wr + mb * 16 + quad * 4 + r;
                float* orow = out + (size_t)(b * S_ + srow) * (H_ * D_) + h * D_;
                #pragma unroll
                for (int db = 0; db < 8; ++db)
                    orow[db * 16 + l16] = o[mb][db][r] * Lr[mb][r];
            }
    }
}

extern "C" void kernel_launch(void* const* d_in, const int* in_sizes, int n_in,
                              void* d_out, int out_size, void* d_ws, size_t ws_size,
                              hipStream_t stream) {
    // inputs: input_pos, q, k, v, bsz, seqlen, mask, cache_k, cache_v
    const float* q = (const float*)d_in[1];
    const float* k = (const float*)d_in[2];
    const float* v = (const float*)d_in[3];
    float* out = (float*)d_out;
    short* kfr = (short*)d_ws;                           // 8.39 MB bf16 K fragments
    short* vfr = kfr + (size_t)B_ * KVH_ * S_ * D_;      // 8.39 MB bf16 V fragments

    conv_kv<<<512 + 1024, 256, 0, stream>>>(k, v, kfr, vfr);
    fa_fwd<<<dim3(NQP, H_, B_), 256, 0, stream>>>(q, kfr, vfr, out);
}

// Round 12
// 254.438 us; speedup vs baseline: 1.1970x; 1.1970x over previous
//
#include <hip/hip_runtime.h>
#include <hip/hip_bf16.h>

typedef __attribute__((ext_vector_type(8))) short bf16x8;
typedef __attribute__((ext_vector_type(4))) float f32x4;
typedef __attribute__((ext_vector_type(8))) float f32x8;
typedef __attribute__((ext_vector_type(2))) float f32x2;
typedef __attribute__((ext_vector_type(8))) __bf16 bfv8;
typedef __attribute__((ext_vector_type(4))) __bf16 bfv4;
typedef __attribute__((ext_vector_type(2))) __bf16 bfv2;
typedef __attribute__((ext_vector_type(2))) unsigned int u32x2;

#define B_ 2
#define S_ 2048
#define H_ 32
#define KVH_ 8
#define D_ 128
#define BM 128
#define BN 64
#define NQT (S_ / BM)   // 16
#define NQP (NQT / 2)   // 8 q-tile pairs
#define VTILEF 8192     // shorts per fragment-major V tile (16 frags x 64 lanes x 8)

__device__ __forceinline__ bf16x8 cvt8(f32x8 v) {
    union { bfv8 b; bf16x8 s; } u;
    u.b = __builtin_convertvector(v, bfv8);
    return u.s;
}

// direct global->LDS DMA (16B per lane, wave-uniform LDS base + lane*16)
#define GLD16(g, l) __builtin_amdgcn_global_load_lds(                     \
    (const __attribute__((address_space(1))) unsigned int*)(g),           \
    (__attribute__((address_space(3))) unsigned int*)(l), 16, 0, 0)

// ---- merged pre-pass ----
// blocks [0,2048):    K fp32 -> bf16 row-major (for LDS staging in fa)
// blocks [2048,3072): V fp32 -> bf16 sigma-transpose FRAGMENT-MAJOR tiles
//   (r11-verified): per (z,ti) tile, fragment fi = kk*8+db, lane ln: 16B
//   slice at vfr + (z*32+ti)*8192 + fi*512 + ln*8 -> fa's vf loads are
//   perfectly coalesced 1KB wave loads from L2.
__global__ __launch_bounds__(256) void conv_kv(const float* __restrict__ k,
                                               const float* __restrict__ v,
                                               short* __restrict__ kws,
                                               short* __restrict__ vfr) {
    __shared__ short tl[64 * 68];
    const int tid = threadIdx.x;
    if (blockIdx.x < 2048) {
        const int idx = (blockIdx.x * 256 + tid) * 8;
        f32x8 a = *(const f32x8*)(k + idx);
        *(bf16x8*)(kws + idx) = cvt8(a);
    } else {
        const int f  = blockIdx.x - 2048;
        const int d0 = (f & 1) * 64;
        const int ti = (f >> 1) & 31;
        const int z  = f >> 6;
        const float* vb = v + ((size_t)z * S_ + ti * 64) * D_;
        #pragma unroll
        for (int i = 0; i < 4; ++i) {
            const int chunk = i * 256 + tid;
            const int tr = chunk >> 4;
            const int c4 = (chunk & 15) << 2;
            float4 fv = *(const float4*)(vb + (size_t)tr * D_ + d0 + c4);
            union { bfv4 b; ushort4 s; } u;
            u.b = __builtin_convertvector((f32x4){fv.x, fv.y, fv.z, fv.w}, bfv4);
            *(ushort4*)(&tl[tr * 68 + c4]) = u.s;
        }
        __syncthreads();
        short* dst = vfr + (size_t)(z * 32 + ti) * VTILEF;
        #pragma unroll
        for (int i = 0; i < 2; ++i) {
            const int chunk = i * 256 + tid;     // 512 cells: 8 fx x 64 lanes
            const int fx = chunk >> 6;           // kk*4 + db_loc
            const int ln = chunk & 63;           // qv*16 + l16v
            const int kk = fx >> 2, dbl = fx & 3;
            const int qv = ln >> 4, l16v = ln & 15;
            const int dl = dbl * 16 + l16v;      // local d 0..63
            const int sg = kk * 4 + qv;          // slot group 0..7
            bf16x8 r;
            #pragma unroll
            for (int w = 0; w < 8; ++w) {
                const int t = 2 * sg + (w >> 2) + 16 * (w & 3);  // sigma^-1(8sg+w)
                r[w] = tl[t * 68 + dl];
            }
            const int fi = kk * 8 + (d0 >> 4) + dbl;
            *(bf16x8*)(dst + ((size_t)fi * 64 + ln) * 8) = r;
        }
    }
}

// stage K tile ti into LDS buffer bufi (4 global_load_lds per wave)
#define STAGEK(ti_, bufi_)  do {                                           \
    const short* kt2_ = kt + (ti_) * (BN * D_);                            \
    short* kdst_ = &lds_k[bufi_][0];                                       \
    _Pragma("unroll")                                                      \
    for (int rd_ = 0; rd_ < 4; ++rd_) {                                    \
        const int slot_ = rd_ * 256 + tid;                                 \
        const int r_  = slot_ >> 4;                                        \
        const int cg_ = (slot_ & 15) ^ (r_ & 7);                           \
        GLD16(kt2_ + r_ * D_ + cg_ * 8, kdst_ + (rd_ * 256 + wave * 64) * 8); \
    }                                                                      \
} while (0)

// ---- main flash-attention kernel: K via LDS (r7-proven), V direct L2 ----
// r7 vs r11 isolation: K latency is unhideable at consumption (must stage/
// prefetch via LDS); V consumption is ~500cyc after a natural issue point
// (post-QK^T) -> fragment-major direct loads hide fully. Hybrid: K dbuf-LDS
// + counted vmcnt; V = two 8x1KB coalesced L2 load batches (vf0 under
// softmax+P-roundtrip, vf1 under PV kk=0). LDS 40KB (K 2x16 + P 8).
// KEY INVARIANTS: causal pairing {qp,15-qp} (r6); vf shared across both mb
// (r5); launch_bounds min-occ 2 (r4: higher = 64-VGPR spill cliff);
// V-direct needs fragment-major layout (r9: strided lanes = disaster).
// Watch: WRITE_SIZE must stay 65.5MB (no spill; VGPR ~140 expected).
__global__ __launch_bounds__(256, 2) void fa_fwd(
    const float* __restrict__ q, const short* __restrict__ kws,
    const short* __restrict__ vfr, float* __restrict__ out)
{
    __shared__ short lds_k[2][64 * 128];  // 32 KB (K rows t, cols d; chunk^=(t&7))
    __shared__ short lds_p[4 * 16 * 64];  // 8 KB  (per-wave 16x64 P, two passes)

    // ---- XCD-aware block swizzle (T1): each XCD owns 2 (b,kvh) groups ----
    const int flat = blockIdx.x + NQP * (blockIdx.y + H_ * blockIdx.z);
    const int xcd  = flat & 7;
    const int idx  = flat >> 3;              // 0..63 dispatch order within XCD
    const int work = xcd * 64 + idx;         // contiguous work chunk per XCD
    const int bkvh = work >> 5;              // 0..15 = b*KVH + kvh
    const int rem  = work & 31;
    const int qp   = rem >> 2;               // 0..7 pair index
    const int b    = bkvh >> 3;
    const int kvh  = bkvh & 7;
    const int h    = (kvh << 2) | (rem & 3); // 4 heads of the group adjacent

    const int tid  = threadIdx.x;
    const int wave = __builtin_amdgcn_readfirstlane(tid >> 6);
    const int lane = tid & 63;
    const int quad = lane >> 4;
    const int l16  = lane & 15;
    const int x7   = l16 & 7;

    const float sl2e = 0.08838834764831843f * 1.4426950408889634f; // scale*log2e

    const short* kt = kws + (size_t)(b * KVH_ + kvh) * S_ * D_;
    const short* vt = vfr + (size_t)(b * KVH_ + kvh) * 32 * VTILEF;
    short* pw = lds_p + wave * 1024;   // wave-private 16x64

    #pragma unroll 1
    for (int phase = 0; phase < 2; ++phase) {
        const int qt = phase ? (NQT - 1 - qp) : qp;
        const int wr = qt * BM + wave * 32;    // wave's first query row
        const int nt = 2 * qt + 2;

        // issue tile-0 K staging ASAP; latency hides under Q load+convert
        STAGEK(0, 0);

        // Q fragments (A-layout), pre-scaled by scale*log2e
        bf16x8 qf[2][4];
        #pragma unroll
        for (int mb = 0; mb < 2; ++mb) {
            const float* qrow = q + (size_t)((b * S_ + wr + mb * 16 + l16) * H_ + h) * D_;
            #pragma unroll
            for (int c = 0; c < 4; ++c) {
                f32x8 a = *(const f32x8*)(qrow + c * 32 + quad * 8);
                qf[mb][c] = cvt8(a * sl2e);
            }
        }

        f32x4 o[2][8];
        #pragma unroll
        for (int mb = 0; mb < 2; ++mb)
            #pragma unroll
            for (int db = 0; db < 8; ++db) o[mb][db] = (f32x4){0.f, 0.f, 0.f, 0.f};
        float Lr[2][4] = {{0.f,0.f,0.f,0.f},{0.f,0.f,0.f,0.f}};

        int bi = 0;
        for (int ti = 0; ti < nt; ++ti) {
            // prefetch next K tile; counted vmcnt drains only tile-ti's DMAs
            if (ti + 1 < nt) {
                STAGEK(ti + 1, bi ^ 1);
                asm volatile("s_waitcnt vmcnt(4)" ::: "memory");
            } else {
                asm volatile("s_waitcnt vmcnt(0)" ::: "memory");
            }
            __builtin_amdgcn_s_barrier();      // all waves' K(ti) visible
            __builtin_amdgcn_sched_barrier(0);

            const int t0 = ti * BN;
            if (t0 <= wr + 31) {   // wave-uniform: skip fully-masked tiles
                const short* kb = &lds_k[bi][0];
                const short* vfb = vt + (size_t)ti * VTILEF;

                // ---- S = Q K^T (K from LDS, prefetched) ----
                f32x4 sc[2][4];
                #pragma unroll
                for (int mb = 0; mb < 2; ++mb)
                    #pragma unroll
                    for (int nb = 0; nb < 4; ++nb) sc[mb][nb] = (f32x4){0.f,0.f,0.f,0.f};
                __builtin_amdgcn_s_setprio(1);
                #pragma unroll
                for (int c = 0; c < 4; ++c) {
                    #pragma unroll
                    for (int nb = 0; nb < 4; ++nb) {
                        bf16x8 kf = *(const bf16x8*)(&kb[(nb * 16 + l16) * 128 +
                                                         (((c * 4 + quad) ^ x7) * 8)]);
                        sc[0][nb] = __builtin_amdgcn_mfma_f32_16x16x32_bf16(qf[0][c], kf, sc[0][nb], 0, 0, 0);
                        sc[1][nb] = __builtin_amdgcn_mfma_f32_16x16x32_bf16(qf[1][c], kf, sc[1][nb], 0, 0, 0);
                    }
                }
                __builtin_amdgcn_s_setprio(0);

                // ---- vf kk=0: issue NOW; latency hides under softmax + P ----
                bf16x8 vf0[8];
                #pragma unroll
                for (int db = 0; db < 8; ++db)
                    vf0[db] = *(const bf16x8*)(vfb + ((size_t)db * 64 + lane) * 8);

                // ---- softmax, fixed basis ----
                const bool needmask = (t0 + BN - 1 > wr);
                if (needmask) {
                    #pragma unroll
                    for (int mb = 0; mb < 2; ++mb)
                        #pragma unroll
                        for (int nb = 0; nb < 4; ++nb)
                            #pragma unroll
                            for (int r = 0; r < 4; ++r) {
                                const int tcol = t0 + nb * 16 + l16;
                                const int srow = wr + mb * 16 + quad * 4 + r;
                                if (tcol > srow) sc[mb][nb][r] = -1e30f;
                            }
                }
                #pragma unroll
                for (int mb = 0; mb < 2; ++mb)
                    #pragma unroll
                    for (int nb = 0; nb < 4; ++nb)
                        #pragma unroll
                        for (int r = 0; r < 4; ++r)
                            sc[mb][nb][r] = exp2f(sc[mb][nb][r]);
                #pragma unroll
                for (int mb = 0; mb < 2; ++mb)
                    #pragma unroll
                    for (int r = 0; r < 4; ++r)
                        Lr[mb][r] += (sc[mb][0][r] + sc[mb][1][r]) + (sc[mb][2][r] + sc[mb][3][r]);

                // ---- P -> LDS in two 16-row passes (wave-private), pf -> regs ----
                bf16x8 pf[2][2];
                #pragma unroll
                for (int mb = 0; mb < 2; ++mb) {
                    #pragma unroll
                    for (int r = 0; r < 4; ++r) {
                        const int rw = quad * 4 + r;
                        union { bfv2 b; unsigned u; } p0, p1;
                        p0.b = __builtin_convertvector((f32x2){sc[mb][0][r], sc[mb][1][r]}, bfv2);
                        p1.b = __builtin_convertvector((f32x2){sc[mb][2][r], sc[mb][3][r]}, bfv2);
                        *(u32x2*)(&pw[rw * 64 + (((l16 >> 1) ^ (rw & 7)) * 8) + (l16 & 1) * 4]) =
                            (u32x2){p0.u, p1.u};
                    }
                    #pragma unroll
                    for (int kk = 0; kk < 2; ++kk)
                        pf[mb][kk] = *(const bf16x8*)(&pw[l16 * 64 +
                                                         (((kk * 4 + quad) ^ x7) * 8)]);
                }

                // ---- vf kk=1: issue; lands under PV kk=0 MFMAs ----
                bf16x8 vf1[8];
                #pragma unroll
                for (int db = 0; db < 8; ++db)
                    vf1[db] = *(const bf16x8*)(vfb + ((size_t)(8 + db) * 64 + lane) * 8);

                // ---- O += P V: vf in regs, shared across both mb blocks ----
                __builtin_amdgcn_s_setprio(1);
                #pragma unroll
                for (int db = 0; db < 8; ++db) {
                    o[0][db] = __builtin_amdgcn_mfma_f32_16x16x32_bf16(pf[0][0], vf0[db], o[0][db], 0, 0, 0);
                    o[1][db] = __builtin_amdgcn_mfma_f32_16x16x32_bf16(pf[1][0], vf0[db], o[1][db], 0, 0, 0);
                }
                #pragma unroll
                for (int db = 0; db < 8; ++db) {
                    o[0][db] = __builtin_amdgcn_mfma_f32_16x16x32_bf16(pf[0][1], vf1[db], o[0][db], 0, 0, 0);
                    o[1][db] = __builtin_amdgcn_mfma_f32_16x16x32_bf16(pf[1][1], vf1[db], o[1][db], 0, 0, 0);
                }
                __builtin_amdgcn_s_setprio(0);
            }

            // compute on K buffer bi done (all waves) before iter ti+1 restages it
            __builtin_amdgcn_s_barrier();
            __builtin_amdgcn_sched_barrier(0);
            bi ^= 1;
        }

        // ---- epilogue for this q-tile: L-reduce, scale, store ----
        #pragma unroll
        for (int mb = 0; mb < 2; ++mb)
            #pragma unroll
            for (int r = 0; r < 4; ++r) {
                float l = Lr[mb][r];
                l += __shfl_xor(l, 1, 16);
                l += __shfl_xor(l, 2, 16);
                l += __shfl_xor(l, 4, 16);
                l += __shfl_xor(l, 8, 16);
                Lr[mb][r] = 1.0f / l;
            }
        #pragma unroll
        for (int mb = 0; mb < 2; ++mb)
            #pragma unroll
            for (int r = 0; r < 4; ++r) {
                const int srow = wr + mb * 16 + quad * 4 + r;
                float* orow = out + (size_t)(b * S_ + srow) * (H_ * D_) + h * D_;
                #pragma unroll
                for (int db = 0; db < 8; ++db)
                    orow[db * 16 + l16] = o[mb][db][r] * Lr[mb][r];
            }
        // all waves passed the loop-end barrier -> phase B may restage buffer 0
    }
}

extern "C" void kernel_launch(void* const* d_in, const int* in_sizes, int n_in,
                              void* d_out, int out_size, void* d_ws, size_t ws_size,
                              hipStream_t stream) {
    // inputs: input_pos, q, k, v, bsz, seqlen, mask, cache_k, cache_v
    const float* q = (const float*)d_in[1];
    const float* k = (const float*)d_in[2];
    const float* v = (const float*)d_in[3];
    float* out = (float*)d_out;
    short* kws = (short*)d_ws;                           // 8.39 MB bf16 K row-major
    short* vfr = kws + (size_t)B_ * KVH_ * S_ * D_;      // 8.39 MB bf16 V frag-major

    conv_kv<<<2048 + 1024, 256, 0, stream>>>(k, v, kws, vfr);
    fa_fwd<<<dim3(NQP, H_, B_), 256, 0, stream>>>(q, kws, vfr, out);
}

// Round 13
// 249.153 us; speedup vs baseline: 1.2224x; 1.0212x over previous
//
#include <hip/hip_runtime.h>
#include <hip/hip_bf16.h>

typedef __attribute__((ext_vector_type(8))) short bf16x8;
typedef __attribute__((ext_vector_type(4))) float f32x4;
typedef __attribute__((ext_vector_type(8))) float f32x8;
typedef __attribute__((ext_vector_type(2))) float f32x2;
typedef __attribute__((ext_vector_type(8))) __bf16 bfv8;
typedef __attribute__((ext_vector_type(4))) __bf16 bfv4;
typedef __attribute__((ext_vector_type(2))) __bf16 bfv2;
typedef __attribute__((ext_vector_type(2))) unsigned int u32x2;

#define B_ 2
#define S_ 2048
#define H_ 32
#define KVH_ 8
#define D_ 128
#define BM 128
#define BN 64
#define NQT (S_ / BM)   // 16
#define NQP (NQT / 2)   // 8 q-tile pairs
#define VTILEF 8192     // shorts per fragment-major V tile (16 frags x 64 lanes x 8)

__device__ __forceinline__ bf16x8 cvt8(f32x8 v) {
    union { bfv8 b; bf16x8 s; } u;
    u.b = __builtin_convertvector(v, bfv8);
    return u.s;
}

// direct global->LDS DMA (16B per lane, wave-uniform LDS base + lane*16)
#define GLD16(g, l) __builtin_amdgcn_global_load_lds(                     \
    (const __attribute__((address_space(1))) unsigned int*)(g),           \
    (__attribute__((address_space(3))) unsigned int*)(l), 16, 0, 0)

// ---- merged pre-pass ----
// blocks [0,2048):    K fp32 -> bf16 row-major (for LDS staging in fa)
// blocks [2048,3072): V fp32 -> bf16 sigma-transpose FRAGMENT-MAJOR tiles
//   (r11/r12-verified): per (z,ti) tile, fragment fi = kk*8+db, lane ln: 16B
//   slice at vfr + (z*32+ti)*8192 + fi*512 + ln*8 -> fa's vf loads are
//   perfectly coalesced 1KB wave loads from L2.
__global__ __launch_bounds__(256) void conv_kv(const float* __restrict__ k,
                                               const float* __restrict__ v,
                                               short* __restrict__ kws,
                                               short* __restrict__ vfr) {
    __shared__ short tl[64 * 68];
    const int tid = threadIdx.x;
    if (blockIdx.x < 2048) {
        const int idx = (blockIdx.x * 256 + tid) * 8;
        f32x8 a = *(const f32x8*)(k + idx);
        *(bf16x8*)(kws + idx) = cvt8(a);
    } else {
        const int f  = blockIdx.x - 2048;
        const int d0 = (f & 1) * 64;
        const int ti = (f >> 1) & 31;
        const int z  = f >> 6;
        const float* vb = v + ((size_t)z * S_ + ti * 64) * D_;
        #pragma unroll
        for (int i = 0; i < 4; ++i) {
            const int chunk = i * 256 + tid;
            const int tr = chunk >> 4;
            const int c4 = (chunk & 15) << 2;
            float4 fv = *(const float4*)(vb + (size_t)tr * D_ + d0 + c4);
            union { bfv4 b; ushort4 s; } u;
            u.b = __builtin_convertvector((f32x4){fv.x, fv.y, fv.z, fv.w}, bfv4);
            *(ushort4*)(&tl[tr * 68 + c4]) = u.s;
        }
        __syncthreads();
        short* dst = vfr + (size_t)(z * 32 + ti) * VTILEF;
        #pragma unroll
        for (int i = 0; i < 2; ++i) {
            const int chunk = i * 256 + tid;     // 512 cells: 8 fx x 64 lanes
            const int fx = chunk >> 6;           // kk*4 + db_loc
            const int ln = chunk & 63;           // qv*16 + l16v
            const int kk = fx >> 2, dbl = fx & 3;
            const int qv = ln >> 4, l16v = ln & 15;
            const int dl = dbl * 16 + l16v;      // local d 0..63
            const int sg = kk * 4 + qv;          // slot group 0..7
            bf16x8 r;
            #pragma unroll
            for (int w = 0; w < 8; ++w) {
                const int t = 2 * sg + (w >> 2) + 16 * (w & 3);  // sigma^-1(8sg+w)
                r[w] = tl[t * 68 + dl];
            }
            const int fi = kk * 8 + (d0 >> 4) + dbl;
            *(bf16x8*)(dst + ((size_t)fi * 64 + ln) * 8) = r;
        }
    }
}

// stage K tile ti into LDS buffer bufi (4 global_load_lds per wave)
#define STAGEK(ti_, bufi_)  do {                                           \
    const short* kt2_ = kt + (ti_) * (BN * D_);                            \
    short* kdst_ = &lds_k[bufi_][0];                                       \
    _Pragma("unroll")                                                      \
    for (int rd_ = 0; rd_ < 4; ++rd_) {                                    \
        const int slot_ = rd_ * 256 + tid;                                 \
        const int r_  = slot_ >> 4;                                        \
        const int cg_ = (slot_ & 15) ^ (r_ & 7);                           \
        GLD16(kt2_ + r_ * D_ + cg_ * 8, kdst_ + (rd_ * 256 + wave * 64) * 8); \
    }                                                                      \
} while (0)

// ---- main flash-attention kernel ----
// K via triple-buffered LDS, ONE barrier per iteration; V direct from L2
// (fragment-major). r12 post-mortem: LDS throughput is NOT the limit
// (removing V reads bought 2%); r11: zero-barrier-but-K-direct slower (K
// latency unhideable at consumption). Remaining cost model: 72 lockstep
// points/block x slowest-wave serial chain. Triple buffer makes the single
// top-of-iter barrier sufficient: stage(ti+1) targets buf[(ti+1)%3], last
// consumed at ti-2, and barrier(ti) guarantees all waves finished ti-1.
// KEY INVARIANTS: causal pairing {qp,15-qp} (r6); vf shared across both mb
// (r5); launch_bounds min-occ 2 (r4: higher = 64-VGPR spill cliff; r8:
// absent lets allocator pick 128 + spill at high liveness); V-direct needs
// fragment-major layout (r9: strided lanes disaster). Grid=512 caps
// occupancy at 2 blocks/CU, so LDS 56KB is free.
// Watch: WRITE_SIZE must stay ~65.5MB (no spill).
__global__ __launch_bounds__(256, 2) void fa_fwd(
    const float* __restrict__ q, const short* __restrict__ kws,
    const short* __restrict__ vfr, float* __restrict__ out)
{
    __shared__ short lds_k[3][64 * 128];  // 48 KB (K rows t, cols d; chunk^=(t&7))
    __shared__ short lds_p[4 * 16 * 64];  // 8 KB  (per-wave 16x64 P, two passes)

    // ---- XCD-aware block swizzle (T1): each XCD owns 2 (b,kvh) groups ----
    const int flat = blockIdx.x + NQP * (blockIdx.y + H_ * blockIdx.z);
    const int xcd  = flat & 7;
    const int idx  = flat >> 3;              // 0..63 dispatch order within XCD
    const int work = xcd * 64 + idx;         // contiguous work chunk per XCD
    const int bkvh = work >> 5;              // 0..15 = b*KVH + kvh
    const int rem  = work & 31;
    const int qp   = rem >> 2;               // 0..7 pair index
    const int b    = bkvh >> 3;
    const int kvh  = bkvh & 7;
    const int h    = (kvh << 2) | (rem & 3); // 4 heads of the group adjacent

    const int tid  = threadIdx.x;
    const int wave = __builtin_amdgcn_readfirstlane(tid >> 6);
    const int lane = tid & 63;
    const int quad = lane >> 4;
    const int l16  = lane & 15;
    const int x7   = l16 & 7;

    const float sl2e = 0.08838834764831843f * 1.4426950408889634f; // scale*log2e

    const short* kt = kws + (size_t)(b * KVH_ + kvh) * S_ * D_;
    const short* vt = vfr + (size_t)(b * KVH_ + kvh) * 32 * VTILEF;
    short* pw = lds_p + wave * 1024;   // wave-private 16x64

    #pragma unroll 1
    for (int phase = 0; phase < 2; ++phase) {
        const int qt = phase ? (NQT - 1 - qp) : qp;
        const int wr = qt * BM + wave * 32;    // wave's first query row
        const int nt = 2 * qt + 2;

        // phase B: ensure no wave still reads phase-A K buffers before restage
        if (phase) {
            __builtin_amdgcn_s_barrier();
            __builtin_amdgcn_sched_barrier(0);
        }
        // issue tile-0 K staging ASAP; latency hides under Q load+convert
        STAGEK(0, 0);

        // Q fragments (A-layout), pre-scaled by scale*log2e
        bf16x8 qf[2][4];
        #pragma unroll
        for (int mb = 0; mb < 2; ++mb) {
            const float* qrow = q + (size_t)((b * S_ + wr + mb * 16 + l16) * H_ + h) * D_;
            #pragma unroll
            for (int c = 0; c < 4; ++c) {
                f32x8 a = *(const f32x8*)(qrow + c * 32 + quad * 8);
                qf[mb][c] = cvt8(a * sl2e);
            }
        }

        f32x4 o[2][8];
        #pragma unroll
        for (int mb = 0; mb < 2; ++mb)
            #pragma unroll
            for (int db = 0; db < 8; ++db) o[mb][db] = (f32x4){0.f, 0.f, 0.f, 0.f};
        float Lr[2][4] = {{0.f,0.f,0.f,0.f},{0.f,0.f,0.f,0.f}};

        int bi = 0;                 // = ti % 3
        int bnext = 1;              // = (ti+1) % 3
        for (int ti = 0; ti < nt; ++ti) {
            // stage tile ti+1 into buf[(ti+1)%3] (consumed last at ti-2 ->
            // safe: barrier(ti-1) proved all waves finished ti-2). Counted
            // vmcnt drains ONLY tile-ti's 4 DMAs; ti+1's stay in flight.
            if (ti + 1 < nt) {
                STAGEK(ti + 1, bnext);
                asm volatile("s_waitcnt vmcnt(4)" ::: "memory");
            } else {
                asm volatile("s_waitcnt vmcnt(0)" ::: "memory");
            }
            __builtin_amdgcn_s_barrier();      // all waves: K(ti) visible,
            __builtin_amdgcn_sched_barrier(0); // compute(ti-1) done everywhere

            const int t0 = ti * BN;
            if (t0 <= wr + 31) {   // wave-uniform: skip fully-masked tiles
                const short* kb = &lds_k[bi][0];
                const short* vfb = vt + (size_t)ti * VTILEF;

                // ---- S = Q K^T (K from LDS, prefetched) ----
                f32x4 sc[2][4];
                #pragma unroll
                for (int mb = 0; mb < 2; ++mb)
                    #pragma unroll
                    for (int nb = 0; nb < 4; ++nb) sc[mb][nb] = (f32x4){0.f,0.f,0.f,0.f};
                __builtin_amdgcn_s_setprio(1);
                #pragma unroll
                for (int c = 0; c < 4; ++c) {
                    #pragma unroll
                    for (int nb = 0; nb < 4; ++nb) {
                        bf16x8 kf = *(const bf16x8*)(&kb[(nb * 16 + l16) * 128 +
                                                         (((c * 4 + quad) ^ x7) * 8)]);
                        sc[0][nb] = __builtin_amdgcn_mfma_f32_16x16x32_bf16(qf[0][c], kf, sc[0][nb], 0, 0, 0);
                        sc[1][nb] = __builtin_amdgcn_mfma_f32_16x16x32_bf16(qf[1][c], kf, sc[1][nb], 0, 0, 0);
                    }
                }
                __builtin_amdgcn_s_setprio(0);

                // ---- vf kk=0: issue NOW; latency hides under softmax + P ----
                bf16x8 vf0[8];
                #pragma unroll
                for (int db = 0; db < 8; ++db)
                    vf0[db] = *(const bf16x8*)(vfb + ((size_t)db * 64 + lane) * 8);

                // ---- softmax, fixed basis ----
                const bool needmask = (t0 + BN - 1 > wr);
                if (needmask) {
                    #pragma unroll
                    for (int mb = 0; mb < 2; ++mb)
                        #pragma unroll
                        for (int nb = 0; nb < 4; ++nb)
                            #pragma unroll
                            for (int r = 0; r < 4; ++r) {
                                const int tcol = t0 + nb * 16 + l16;
                                const int srow = wr + mb * 16 + quad * 4 + r;
                                if (tcol > srow) sc[mb][nb][r] = -1e30f;
                            }
                }
                #pragma unroll
                for (int mb = 0; mb < 2; ++mb)
                    #pragma unroll
                    for (int nb = 0; nb < 4; ++nb)
                        #pragma unroll
                        for (int r = 0; r < 4; ++r)
                            sc[mb][nb][r] = exp2f(sc[mb][nb][r]);
                #pragma unroll
                for (int mb = 0; mb < 2; ++mb)
                    #pragma unroll
                    for (int r = 0; r < 4; ++r)
                        Lr[mb][r] += (sc[mb][0][r] + sc[mb][1][r]) + (sc[mb][2][r] + sc[mb][3][r]);

                // ---- P -> LDS in two 16-row passes (wave-private), pf -> regs ----
                bf16x8 pf[2][2];
                #pragma unroll
                for (int mb = 0; mb < 2; ++mb) {
                    #pragma unroll
                    for (int r = 0; r < 4; ++r) {
                        const int rw = quad * 4 + r;
                        union { bfv2 b; unsigned u; } p0, p1;
                        p0.b = __builtin_convertvector((f32x2){sc[mb][0][r], sc[mb][1][r]}, bfv2);
                        p1.b = __builtin_convertvector((f32x2){sc[mb][2][r], sc[mb][3][r]}, bfv2);
                        *(u32x2*)(&pw[rw * 64 + (((l16 >> 1) ^ (rw & 7)) * 8) + (l16 & 1) * 4]) =
                            (u32x2){p0.u, p1.u};
                    }
                    #pragma unroll
                    for (int kk = 0; kk < 2; ++kk)
                        pf[mb][kk] = *(const bf16x8*)(&pw[l16 * 64 +
                                                         (((kk * 4 + quad) ^ x7) * 8)]);
                }

                // ---- vf kk=1: issue; lands under PV kk=0 MFMAs ----
                bf16x8 vf1[8];
                #pragma unroll
                for (int db = 0; db < 8; ++db)
                    vf1[db] = *(const bf16x8*)(vfb + ((size_t)(8 + db) * 64 + lane) * 8);

                // ---- O += P V: vf in regs, shared across both mb blocks ----
                __builtin_amdgcn_s_setprio(1);
                #pragma unroll
                for (int db = 0; db < 8; ++db) {
                    o[0][db] = __builtin_amdgcn_mfma_f32_16x16x32_bf16(pf[0][0], vf0[db], o[0][db], 0, 0, 0);
                    o[1][db] = __builtin_amdgcn_mfma_f32_16x16x32_bf16(pf[1][0], vf0[db], o[1][db], 0, 0, 0);
                }
                #pragma unroll
                for (int db = 0; db < 8; ++db) {
                    o[0][db] = __builtin_amdgcn_mfma_f32_16x16x32_bf16(pf[0][1], vf1[db], o[0][db], 0, 0, 0);
                    o[1][db] = __builtin_amdgcn_mfma_f32_16x16x32_bf16(pf[1][1], vf1[db], o[1][db], 0, 0, 0);
                }
                __builtin_amdgcn_s_setprio(0);
            }

            // NO trailing barrier (triple buffer makes it unnecessary)
            bi = bnext;
            bnext = bnext + 1 == 3 ? 0 : bnext + 1;
        }

        // ---- epilogue for this q-tile: L-reduce, scale, store ----
        #pragma unroll
        for (int mb = 0; mb < 2; ++mb)
            #pragma unroll
            for (int r = 0; r < 4; ++r) {
                float l = Lr[mb][r];
                l += __shfl_xor(l, 1, 16);
                l += __shfl_xor(l, 2, 16);
                l += __shfl_xor(l, 4, 16);
                l += __shfl_xor(l, 8, 16);
                Lr[mb][r] = 1.0f / l;
            }
        #pragma unroll
        for (int mb = 0; mb < 2; ++mb)
            #pragma unroll
            for (int r = 0; r < 4; ++r) {
                const int srow = wr + mb * 16 + quad * 4 + r;
                float* orow = out + (size_t)(b * S_ + srow) * (H_ * D_) + h * D_;
                #pragma unroll
                for (int db = 0; db < 8; ++db)
                    orow[db * 16 + l16] = o[mb][db][r] * Lr[mb][r];
            }
    }
}

extern "C" void kernel_launch(void* const* d_in, const int* in_sizes, int n_in,
                              void* d_out, int out_size, void* d_ws, size_t ws_size,
                              hipStream_t stream) {
    // inputs: input_pos, q, k, v, bsz, seqlen, mask, cache_k, cache_v
    const float* q = (const float*)d_in[1];
    const float* k = (const float*)d_in[2];
    const float* v = (const float*)d_in[3];
    float* out = (float*)d_out;
    short* kws = (short*)d_ws;                           // 8.39 MB bf16 K row-major
    short* vfr = kws + (size_t)B_ * KVH_ * S_ * D_;      // 8.39 MB bf16 V frag-major

    conv_kv<<<2048 + 1024, 256, 0, stream>>>(k, v, kws, vfr);
    fa_fwd<<<dim3(NQP, H_, B_), 256, 0, stream>>>(q, kws, vfr, out);
}